// Round 1
// baseline (809.882 us; speedup 1.0000x reference)
//
#include <hip/hip_runtime.h>

// LJ reduced units: sigma=1, eps=1, cutoff=2.5
// SHIFT = 4*((1/2.5)^12 - (1/2.5)^6) = -0.0163168896
// e_pair = 4*(sr6^2 - sr6) - SHIFT ;  half = 0.5*e_pair
// half = 2*(sr6^2 - sr6) + 0.0081584448
__device__ __forceinline__ float half_lj(float r2) {
    float sr2 = 1.0f / r2;
    float sr6 = sr2 * sr2 * sr2;
    return fmaf(2.0f, sr6 * sr6 - sr6, 0.0081584448f);
}

// One thread handles 4 pairs: loads 2x int4 (pairs) + 3x float4 (distances),
// all 16B-aligned and coalesced. 8 atomicAdds into the 1 MB per-atom output
// (L2-resident).
__global__ void lj_vec4_kernel(const int4* __restrict__ pairs4,
                               const float4* __restrict__ dist4,
                               float* __restrict__ out,
                               int npair4) {
    int t = blockIdx.x * blockDim.x + threadIdx.x;
    if (t >= npair4) return;

    int4 p01 = pairs4[2 * t];
    int4 p23 = pairs4[2 * t + 1];
    float4 d0 = dist4[3 * t];
    float4 d1 = dist4[3 * t + 1];
    float4 d2 = dist4[3 * t + 2];

    // pair0: (d0.x,d0.y,d0.z)  pair1: (d0.w,d1.x,d1.y)
    // pair2: (d1.z,d1.w,d2.x)  pair3: (d2.y,d2.z,d2.w)
    float r2_0 = fmaf(d0.x, d0.x, fmaf(d0.y, d0.y, d0.z * d0.z));
    float r2_1 = fmaf(d0.w, d0.w, fmaf(d1.x, d1.x, d1.y * d1.y));
    float r2_2 = fmaf(d1.z, d1.z, fmaf(d1.w, d1.w, d2.x * d2.x));
    float r2_3 = fmaf(d2.y, d2.y, fmaf(d2.z, d2.z, d2.w * d2.w));

    float h0 = half_lj(r2_0);
    float h1 = half_lj(r2_1);
    float h2 = half_lj(r2_2);
    float h3 = half_lj(r2_3);

    atomicAdd(&out[p01.x], h0);
    atomicAdd(&out[p01.y], h0);
    atomicAdd(&out[p01.z], h1);
    atomicAdd(&out[p01.w], h1);
    atomicAdd(&out[p23.x], h2);
    atomicAdd(&out[p23.y], h2);
    atomicAdd(&out[p23.z], h3);
    atomicAdd(&out[p23.w], h3);
}

// Scalar tail for npairs % 4 != 0 (not hit at P = 8388608, kept for generality).
__global__ void lj_tail_kernel(const int* __restrict__ pairs,
                               const float* __restrict__ dist,
                               float* __restrict__ out,
                               int start, int npairs) {
    int i = start + blockIdx.x * blockDim.x + threadIdx.x;
    if (i >= npairs) return;
    float dx = dist[3 * i + 0];
    float dy = dist[3 * i + 1];
    float dz = dist[3 * i + 2];
    float h = half_lj(fmaf(dx, dx, fmaf(dy, dy, dz * dz)));
    atomicAdd(&out[pairs[2 * i + 0]], h);
    atomicAdd(&out[pairs[2 * i + 1]], h);
}

extern "C" void kernel_launch(void* const* d_in, const int* in_sizes, int n_in,
                              void* d_out, int out_size, void* d_ws, size_t ws_size,
                              hipStream_t stream) {
    const int* pairs = (const int*)d_in[0];      // [P, 2] int32
    const float* dist = (const float*)d_in[1];   // [P, 3] float32
    float* out = (float*)d_out;                  // [n_atoms, 1] float32

    int npairs = in_sizes[0] / 2;
    int npair4 = npairs / 4;
    int tail_start = npair4 * 4;
    int ntail = npairs - tail_start;

    // Zero the per-atom accumulator (graph-capture-safe async memset).
    hipMemsetAsync(d_out, 0, (size_t)out_size * sizeof(float), stream);

    if (npair4 > 0) {
        int block = 256;
        int grid = (npair4 + block - 1) / block;
        lj_vec4_kernel<<<grid, block, 0, stream>>>(
            (const int4*)pairs, (const float4*)dist, out, npair4);
    }
    if (ntail > 0) {
        lj_tail_kernel<<<1, 64, 0, stream>>>(pairs, dist, out, tail_start, npairs);
    }
}